// Round 7
// baseline (190.550 us; speedup 1.0000x reference)
//
#include <hip/hip_runtime.h>
#include <cstddef>
#include <cstdint>

#define B_  4
#define N_  1024
#define D_  1024
#define H_  16
#define DH  64
#define M_  4096   // B_*N_

#define SC2 0.04508422f   // (1/32) * log2(e)  — folded into Q at gemm epilogue

typedef __attribute__((ext_vector_type(4)))  float   f32x4;
typedef __attribute__((ext_vector_type(16))) float   f32x16;
typedef __attribute__((ext_vector_type(8)))  __bf16  bf16x8;
typedef __attribute__((ext_vector_type(4)))  unsigned int u32x4;

#define MFMA(a, b, c)   __builtin_amdgcn_mfma_f32_16x16x32_bf16((a), (b), (c), 0, 0, 0)
#define MFMA32(a, b, c) __builtin_amdgcn_mfma_f32_32x32x16_bf16((a), (b), (c), 0, 0, 0)
#define GLDS(gp, lp) __builtin_amdgcn_global_load_lds( \
    (__attribute__((address_space(1))) void*)(gp),     \
    (__attribute__((address_space(3))) void*)(lp), 16, 0, 0)

static __device__ __forceinline__ unsigned cvtpk(float lo, float hi) {
    unsigned r;
    asm("v_cvt_pk_bf16_f32 %0, %1, %2" : "=v"(r) : "v"(lo), "v"(hi));
    return r;
}

// ---------------------------------------------------------------------------
// convert: fp32 -> bf16 for x (4Mi) and Wq/Wk/Wv/Wc (4x1Mi). [verified R3]
// ---------------------------------------------------------------------------
__global__ __launch_bounds__(256) void convert_k(
    const float* __restrict__ x,  const float* __restrict__ Wq,
    const float* __restrict__ Wk, const float* __restrict__ Wv,
    const float* __restrict__ Wc,
    __bf16* __restrict__ xb, __bf16* __restrict__ wqkvb,
    __bf16* __restrict__ wcb)
{
    const unsigned u = blockIdx.x * 256u + threadIdx.x;
    const unsigned e = u * 8u;
    const float* src;
    __bf16* dst;
    if (e < 4194304u) { src = x + e; dst = xb + e; }
    else {
        const unsigned t2 = e - 4194304u;
        const unsigned wsel = t2 >> 20;
        const unsigned wo = t2 & 1048575u;
        src = (wsel == 0 ? Wq : wsel == 1 ? Wk : wsel == 2 ? Wv : Wc) + wo;
        dst = (wsel < 3 ? wqkvb + (size_t)wsel * 1048576u : wcb) + wo;
    }
    const float4 f0 = *(const float4*)(src);
    const float4 f1 = *(const float4*)(src + 4);
    bf16x8 r;
    r[0] = (__bf16)f0.x; r[1] = (__bf16)f0.y; r[2] = (__bf16)f0.z; r[3] = (__bf16)f0.w;
    r[4] = (__bf16)f1.x; r[5] = (__bf16)f1.y; r[6] = (__bf16)f1.z; r[7] = (__bf16)f1.w;
    *(bf16x8*)dst = r;
}

// ---------------------------------------------------------------------------
// QKV GEMM — R16 [verified: 58.5->42.4us, FETCH 37->24.8MB]: 8-phase 256^2
// template + XCD chunk swizzle + early staging. Byte-identical this round.
// ---------------------------------------------------------------------------
__global__ __launch_bounds__(512, 2) void gemm_qkv256(
    const __bf16* __restrict__ xb, const __bf16* __restrict__ Wb,
    const float* __restrict__ bq, const float* __restrict__ bk,
    const float* __restrict__ bv,
    __bf16* __restrict__ qk_out, __bf16* __restrict__ vT)
{
    __shared__ __bf16 ring[65536];   // [A: 4 x 8192][B: 4 x 8192] = 128KB

    const int tid  = threadIdx.x;
    const int w    = tid >> 6;        // 0..7
    const int lane = tid & 63;
    const int quad = lane >> 4;
    const int l15  = lane & 15;
    const int wr   = w >> 2;          // 0..1  (M half)
    const int wc   = w & 3;           // 0..3  (N quarter)

    const int bid = blockIdx.x;
    const bool VT = (bid >= 128);
    const int xcd = bid & 7;
    int m0, n0;
    const __bf16 *Ap, *Bp;
    if (!VT) {
        const int i  = bid >> 3;               // 0..15 within-XCD
        const int mt = (xcd >> 1) * 4 + (i >> 2);   // 0..15
        const int nt = (xcd & 1) * 4 + (i & 3);     // 0..7
        m0 = mt * 256; n0 = nt * 256;
        Ap = xb; Bp = Wb;
    } else {
        const int i  = (bid - 128) >> 3;       // 0..7
        m0 = (i & 3) * 256;                    // over e (Wv rows)
        n0 = (xcd * 2 + (i >> 2)) * 256;       // over m (xb rows)
        Ap = Wb + (size_t)2 * D_ * D_; Bp = xb;
    }

    const size_t sgl = (size_t)(w * 16 + l15) * D_ + quad * 8;
    const __bf16* Asrc = Ap + (size_t)m0 * D_ + sgl;
    const __bf16* Bsrc = Bp + (size_t)n0 * D_ + sgl;
    __bf16* const ringA = ring;
    __bf16* const ringB = ring + 32768;
    const int sdst = w * 1024;

#define STG_A(tt, h) do {                                               \
    const __bf16* s_ = Asrc + (size_t)(h) * 128 * D_ + (tt) * 64;       \
    __bf16* d_ = ringA + ((((tt) & 1) * 2 + (h)) * 8192) + sdst;        \
    GLDS(s_, d_); GLDS(s_ + 32, d_ + 512); } while (0)
#define STG_B(tt, h) do {                                               \
    const __bf16* s_ = Bsrc + (size_t)(h) * 128 * D_ + (tt) * 64;       \
    __bf16* d_ = ringB + ((((tt) & 1) * 2 + (h)) * 8192) + sdst;        \
    GLDS(s_, d_); GLDS(s_ + 32, d_ + 512); } while (0)

    f32x4 acc[8][4];
    #pragma unroll
    for (int i = 0; i < 8; ++i)
        #pragma unroll
        for (int j = 0; j < 4; ++j)
            acc[i][j] = (f32x4){0.f, 0.f, 0.f, 0.f};

    // prologue: order matters for the vmcnt ledger (oldest = B(0))
    STG_B(0, 0); STG_B(0, 1);
    STG_A(0, 0); STG_A(0, 1);
    STG_B(1, 0); STG_B(1, 1);

    const int rdo = lane * 8;

#define READ_A(q)                                                       \
    afr[0][0] = *(const bf16x8*)(Asl + ((2*(q)  )*2 + 0)*512);          \
    afr[0][1] = *(const bf16x8*)(Asl + ((2*(q)  )*2 + 1)*512);          \
    afr[1][0] = *(const bf16x8*)(Asl + ((2*(q)+1)*2 + 0)*512);          \
    afr[1][1] = *(const bf16x8*)(Asl + ((2*(q)+1)*2 + 1)*512);

#define PHASE_MFMA(q)                                                   \
    __builtin_amdgcn_s_barrier();                                       \
    asm volatile("s_waitcnt lgkmcnt(0)" ::: "memory");                  \
    __builtin_amdgcn_s_setprio(1);                                      \
    _Pragma("unroll")                                                   \
    for (int i = 0; i < 2; ++i)                                         \
      _Pragma("unroll")                                                 \
      for (int nt = 0; nt < 4; ++nt) {                                  \
        acc[2*(q)+i][nt] = MFMA(afr[i][0], bfr[nt][0], acc[2*(q)+i][nt]); \
        acc[2*(q)+i][nt] = MFMA(afr[i][1], bfr[nt][1], acc[2*(q)+i][nt]); \
      }                                                                 \
    __builtin_amdgcn_s_setprio(0);

    for (int t = 0; t < 16; ++t) {
        if (t < 15) asm volatile("s_waitcnt vmcnt(4)" ::: "memory");
        else        asm volatile("s_waitcnt vmcnt(0)" ::: "memory");
        __builtin_amdgcn_s_barrier();

        const __bf16* Asl = ringA + ((t & 1) * 2 + wr) * 8192 + rdo;
        const __bf16* Bsl = ringB + ((t & 1) * 2 + (wc >> 1)) * 8192
                                  + (wc & 1) * 4096 + rdo;
        bf16x8 afr[2][2], bfr[4][2];

        // ---- phase 0: stage both A(t+1) halves ----
        if (t < 15) { STG_A(t + 1, 0); STG_A(t + 1, 1); }
        #pragma unroll
        for (int nt = 0; nt < 4; ++nt) {
            bfr[nt][0] = *(const bf16x8*)(Bsl + (nt * 2 + 0) * 512);
            bfr[nt][1] = *(const bf16x8*)(Bsl + (nt * 2 + 1) * 512);
        }
        READ_A(0)
        PHASE_MFMA(0)
        __builtin_amdgcn_s_barrier();

        // ---- phase 1: stage B(t+2,0) ----
        if (t < 14) STG_B(t + 2, 0);
        READ_A(1)
        PHASE_MFMA(1)
        __builtin_amdgcn_s_barrier();

        // ---- phase 2: stage B(t+2,1) ----
        if (t < 14) STG_B(t + 2, 1);
        READ_A(2)
        PHASE_MFMA(2)
        __builtin_amdgcn_s_barrier();

        // ---- phase 3 ----
        READ_A(3)
        PHASE_MFMA(3)
    }
#undef STG_A
#undef STG_B
#undef READ_A
#undef PHASE_MFMA

    if (!VT) {
        const int zq = n0 >> 10;                  // 0:Q 1:K
        const float* bias = zq ? bk : bq;
        const float qs = zq ? 1.0f : SC2;         // fold softmax scale into Q
        const int nb = (n0 & 1023) + wc * 64;
        float bvv[4];
        #pragma unroll
        for (int nt = 0; nt < 4; ++nt) bvv[nt] = bias[nb + nt * 16 + l15];
        __bf16* C = qk_out + (size_t)zq * M_ * D_;
        #pragma unroll
        for (int mt = 0; mt < 8; ++mt) {
            #pragma unroll
            for (int r = 0; r < 4; ++r) {
                const int row = m0 + wr * 128 + mt * 16 + quad * 4 + r;
                #pragma unroll
                for (int nt = 0; nt < 4; ++nt) {
                    const int col = nb + nt * 16 + l15;
                    const size_t idx = (((size_t)(row >> 10) * H_ + (col >> 6)) * N_
                                        + (row & 1023)) * DH + (col & 63);
                    C[idx] = (__bf16)((acc[mt][nt][r] + bvv[nt]) * qs);
                }
            }
        }
    } else {
        #pragma unroll
        for (int mt = 0; mt < 8; ++mt) {
            #pragma unroll
            for (int r = 0; r < 4; ++r) {
                const int row = m0 + wr * 128 + mt * 16 + quad * 4 + r;   // e
                const float brow = bv[row];
                #pragma unroll
                for (int nt = 0; nt < 4; ++nt) {
                    const int col = n0 + wc * 64 + nt * 16 + l15;         // m
                    const size_t idx = (((size_t)(col >> 10) * H_ + (row >> 6)) * DH
                                        + (row & 63)) * N_ + (col & 1023);
                    vT[idx] = (__bf16)(acc[mt][nt][r] + brow);
                }
            }
        }
    }
}

// ---------------------------------------------------------------------------
// Final projection GEMM — R10's gemm64 MODE0 path [verified; R11 ring null].
// ---------------------------------------------------------------------------
__global__ __launch_bounds__(256, 6) void gemm_out(
    const __bf16* __restrict__ A0, const __bf16* __restrict__ Wb,
    const float* __restrict__ b0, float* __restrict__ Cb)
{
    __shared__ __bf16 As[2048];   // 64x32, frag-ordered (4KB)
    __shared__ __bf16 Bs[4096];   // 128x32, frag-ordered (8KB)

    const int tid  = threadIdx.x;
    const int w    = tid >> 6;
    const int lane = tid & 63;
    const int quad = lane >> 4;
    const int l15  = lane & 15;
    const int wr   = w >> 1, wc = w & 1;

    const int m0 = blockIdx.y * 64;
    const int n0 = blockIdx.x * 128;

    const int Tt = tid >> 6, ko = (tid >> 4) & 3, l = tid & 15;
    const size_t aoff  = (size_t)(m0 + Tt * 16 + l) * D_ + ko * 8;
    const size_t boff1 = (size_t)(n0 + Tt * 16 + l) * D_ + ko * 8;
    const size_t boff2 = boff1 + (size_t)64 * D_;
    __bf16* adst  = As + w * 512;
    __bf16* bdst1 = Bs + w * 512;
    __bf16* bdst2 = Bs + 2048 + w * 512;

    f32x4 acc[2][4];
    #pragma unroll
    for (int i = 0; i < 2; ++i)
        #pragma unroll
        for (int j = 0; j < 4; ++j)
            acc[i][j] = (f32x4){0.f, 0.f, 0.f, 0.f};

    for (int k0 = 0; k0 < D_; k0 += 32) {
        GLDS(A0 + aoff  + k0, adst);
        GLDS(Wb + boff1 + k0, bdst1);
        GLDS(Wb + boff2 + k0, bdst2);
        __syncthreads();

        bf16x8 af[2], bf[4];
        #pragma unroll
        for (int mt = 0; mt < 2; ++mt)
            af[mt] = *(const bf16x8*)(As + (((wr * 2 + mt) * 4 + quad) * 16 + l15) * 8);
        #pragma unroll
        for (int nt = 0; nt < 4; ++nt)
            bf[nt] = *(const bf16x8*)(Bs + (((wc * 4 + nt) * 4 + quad) * 16 + l15) * 8);
        #pragma unroll
        for (int mt = 0; mt < 2; ++mt)
            #pragma unroll
            for (int nt = 0; nt < 4; ++nt)
                acc[mt][nt] = MFMA(af[mt], bf[nt], acc[mt][nt]);
        __syncthreads();
    }

    float bvv[4];
    #pragma unroll
    for (int nt = 0; nt < 4; ++nt)
        bvv[nt] = b0[n0 + wc * 64 + nt * 16 + l15];
    #pragma unroll
    for (int mt = 0; mt < 2; ++mt) {
        #pragma unroll
        for (int r = 0; r < 4; ++r) {
            const int row = m0 + (wr * 2 + mt) * 16 + quad * 4 + r;
            #pragma unroll
            for (int nt = 0; nt < 4; ++nt) {
                const int col = n0 + wc * 64 + nt * 16 + l15;
                Cb[(size_t)row * D_ + col] = acc[mt][nt][r] + bvv[nt];
            }
        }
    }
}

// ---------------------------------------------------------------------------
// MFMA flash attention v9 — R17: K-split doubles TLP. v8's decomposition
// (32 q/wave, 16 K-tiles) yields 2048 waves total = 2.0/SIMD device-wide —
// a structural TLP cap; the serial QK->exp->pack->PV chain is exposed.
// v9: 8-wave blocks; wave (qw=w>>1, ks=w&1) processes q-subtile qw against
// key-half ks (8 tiles each). No-max softmax => partial Ov/psum are DIRECTLY
// additive; end combine = one 33KB LDS round-trip (stride-33 pad, 2-way
// bank alias = free). 4096 waves = 4/SIMD. Compute/PACK/staging math is
// R15-verified code with w->qw and per-set K/V bases [ledger re-checked].
// LDS 34KB; __launch_bounds__(512,4) pins 2 blocks/CU.
// ---------------------------------------------------------------------------
__global__ __launch_bounds__(512, 4) void attn_mfma(
    const __bf16* __restrict__ qh, const __bf16* __restrict__ kh,
    const __bf16* __restrict__ vT, __bf16* __restrict__ ob)
{
    // overlay: staging (2 sets x (K 8KB + V 8KB) = 32KB) / combine (33792B)
    __shared__ __align__(16) float smem_f[8448];
    __bf16* const smem16 = (__bf16*)smem_f;

    const int tid  = threadIdx.x;
    const int w    = tid >> 6;        // 0..7
    const int qw   = w >> 1;          // 0..3  (q-subtile)
    const int ks   = w & 1;           // 0/1   (key half)
    const int lane = tid & 63;
    const int la31 = lane & 31;
    const int hi   = lane >> 5;       // 0/1

    const int bh = blockIdx.x >> 3;   // 0..63
    const int qt = blockIdx.x & 7;    // 128-q tile
    const int b  = bh >> 4;
    const int h  = bh & 15;

    const size_t headQ = (size_t)(b * H_ + h) * N_;

    // Q in registers: B-frag col=lane&31=q, k=d=(lane>>5)*8+j
    const int qrow = qt * 128 + qw * 32 + la31;
    const __bf16* qp = qh + (headQ + qrow) * DH + hi * 8;
    const bf16x8 qf0 = *(const bf16x8*)(qp);
    const bf16x8 qf1 = *(const bf16x8*)(qp + 16);
    const bf16x8 qf2 = *(const bf16x8*)(qp + 32);
    const bf16x8 qf3 = *(const bf16x8*)(qp + 48);

    // per-set K/V bases: this wave's key half starts at ks*512
    const __bf16* khead = kh + headQ * DH + (size_t)(ks * 512) * DH;     // [512][64]
    const __bf16* vhead = vT + (size_t)(b * H_ + h) * DH * N_ + ks * 512; // [64][N], col off

    // staging offsets [R15-verified, w->qw]:
    const size_t koff0 = (size_t)la31 * DH + qw * 16 + hi * 8;           // frag qw (s=0)
    const size_t koff1 = koff0 + (size_t)32 * DH;                        // frag qw+4
    const size_t voff0 = (size_t)((qw & 1) * 32 + la31) * N_ + (qw >> 1) * 16 + hi * 8;
    const size_t voff1 = voff0 + 32;                                     // frag qw+4
    __bf16* const KsS = smem16 + ks * 4096;            // this set's K region
    __bf16* const VsS = smem16 + 8192 + ks * 4096;     // this set's V region
    const int ltid = qw * 64 + lane;                   // local staging tid (0..255)
    __bf16* const kd0 = KsS + ltid * 8;
    __bf16* const kd1 = KsS + ltid * 8 + 2048;
    __bf16* const vd0 = VsS + ltid * 8;
    __bf16* const vd1 = VsS + ltid * 8 + 2048;

    f32x16 Ov0, Ov1;
    #pragma unroll
    for (int r = 0; r < 16; ++r) { Ov0[r] = 0.f; Ov1[r] = 0.f; }
    float psum = 0.f;

    // prologue: this wave's tile 0 -> regs
    bf16x8 kr0 = *(const bf16x8*)(khead + koff0);
    bf16x8 kr1 = *(const bf16x8*)(khead + koff1);
    bf16x8 vr0 = *(const bf16x8*)(vhead + voff0);
    bf16x8 vr1 = *(const bf16x8*)(vhead + voff1);

#define PACK(earr, base, dst) do {                                        \
    unsigned U_ = cvtpk(earr[(base) + 0], earr[(base) + 1]);              \
    unsigned W_ = cvtpk(earr[(base) + 2], earr[(base) + 3]);              \
    unsigned V_ = cvtpk(earr[(base) + 4], earr[(base) + 5]);              \
    unsigned Z_ = cvtpk(earr[(base) + 6], earr[(base) + 7]);              \
    asm volatile("v_permlane32_swap_b32 %0, %1" : "+v"(U_), "+v"(V_));    \
    asm volatile("v_permlane32_swap_b32 %0, %1" : "+v"(W_), "+v"(Z_));    \
    u32x4 pw_ = {U_, W_, V_, Z_};                                         \
    dst = __builtin_bit_cast(bf16x8, pw_);                                \
} while (0)

    for (int kt = 0; kt < 8; ++kt) {
        asm volatile("s_waitcnt lgkmcnt(0)" ::: "memory");
        __builtin_amdgcn_s_barrier();            // all waves done reading prev tiles
        __builtin_amdgcn_sched_barrier(0);

        *(bf16x8*)kd0 = kr0;                     // implicit vmcnt wait on kr/vr
        *(bf16x8*)kd1 = kr1;
        *(bf16x8*)vd0 = vr0;
        *(bf16x8*)vd1 = vr1;
        if (kt < 7) {                            // issue next-tile loads (this set)
            const __bf16* kp = khead + (size_t)(kt + 1) * 64 * DH;
            const __bf16* vp = vhead + (size_t)(kt + 1) * 64;
            kr0 = *(const bf16x8*)(kp + koff0);
            kr1 = *(const bf16x8*)(kp + koff1);
            vr0 = *(const bf16x8*)(vp + voff0);
            vr1 = *(const bf16x8*)(vp + voff1);
        }
        asm volatile("s_waitcnt lgkmcnt(0)" ::: "memory");   // publish ds_writes only
        __builtin_amdgcn_s_barrier();
        __builtin_amdgcn_sched_barrier(0);

        // ---- QK^T (swapped): sa = K . Q^T over d=64, own set ----
        f32x16 sa0, sa1;
        __builtin_amdgcn_s_setprio(1);
        {
            f32x16 z;
            #pragma unroll
            for (int r = 0; r < 16; ++r) z[r] = 0.f;
            bf16x8 kf;
            kf = *(const bf16x8*)(KsS - ks * 4096 + ks * 4096 + 0 * 512 + lane * 8); sa0 = MFMA32(kf, qf0, z);
            kf = *(const bf16x8*)(KsS + 1 * 512 + lane * 8); sa0 = MFMA32(kf, qf1, sa0);
            kf = *(const bf16x8*)(KsS + 2 * 512 + lane * 8); sa0 = MFMA32(kf, qf2, sa0);
            kf = *(const bf16x8*)(KsS + 3 * 512 + lane * 8); sa0 = MFMA32(kf, qf3, sa0);
            kf = *(const bf16x8*)(KsS + 4 * 512 + lane * 8); sa1 = MFMA32(kf, qf0, z);
            kf = *(const bf16x8*)(KsS + 5 * 512 + lane * 8); sa1 = MFMA32(kf, qf1, sa1);
            kf = *(const bf16x8*)(KsS + 6 * 512 + lane * 8); sa1 = MFMA32(kf, qf2, sa1);
            kf = *(const bf16x8*)(KsS + 7 * 512 + lane * 8); sa1 = MFMA32(kf, qf3, sa1);
        }
        __builtin_amdgcn_s_setprio(0);

        // ---- softmax partials (no max-sub; SC2 pre-folded) ----
        float e0[16], e1[16];
        #pragma unroll
        for (int r = 0; r < 16; ++r) { e0[r] = __builtin_exp2f(sa0[r]); psum += e0[r]; }
        #pragma unroll
        for (int r = 0; r < 16; ++r) { e1[r] = __builtin_exp2f(sa1[r]); psum += e1[r]; }

        // ---- P -> A-frags (T12) ----
        bf16x8 pf0, pf1, pf2, pf3;
        PACK(e0, 0, pf0);
        PACK(e0, 8, pf1);
        PACK(e1, 0, pf2);
        PACK(e1, 8, pf3);

        // ---- PV: O += P . V, own set ----
        __builtin_amdgcn_s_setprio(1);
        {
            bf16x8 vf;
            vf = *(const bf16x8*)(VsS + 0 * 512 + lane * 8); Ov0 = MFMA32(pf0, vf, Ov0);
            vf = *(const bf16x8*)(VsS + 2 * 512 + lane * 8); Ov0 = MFMA32(pf1, vf, Ov0);
            vf = *(const bf16x8*)(VsS + 4 * 512 + lane * 8); Ov0 = MFMA32(pf2, vf, Ov0);
            vf = *(const bf16x8*)(VsS + 6 * 512 + lane * 8); Ov0 = MFMA32(pf3, vf, Ov0);
            vf = *(const bf16x8*)(VsS + 1 * 512 + lane * 8); Ov1 = MFMA32(pf0, vf, Ov1);
            vf = *(const bf16x8*)(VsS + 3 * 512 + lane * 8); Ov1 = MFMA32(pf1, vf, Ov1);
            vf = *(const bf16x8*)(VsS + 5 * 512 + lane * 8); Ov1 = MFMA32(pf2, vf, Ov1);
            vf = *(const bf16x8*)(VsS + 7 * 512 + lane * 8); Ov1 = MFMA32(pf3, vf, Ov1);
        }
        __builtin_amdgcn_s_setprio(0);
    }
#undef PACK

    // fold hi/lo key halves within each wave
    psum += __shfl_xor(psum, 32);

    // ---- cross-ks combine (Ov, psum are additive: no max tracking) ----
    __syncthreads();                               // staging LDS dead -> reuse
    float* const Cb = smem_f;                      // [4][64][33]
    const int cidx = (qw * 64 + lane) * 33;
    if (ks) {
        #pragma unroll
        for (int r = 0; r < 16; ++r) { Cb[cidx + r] = Ov0[r]; Cb[cidx + 16 + r] = Ov1[r]; }
        Cb[cidx + 32] = psum;
    }
    __syncthreads();
    if (ks == 0) {
        #pragma unroll
        for (int r = 0; r < 16; ++r) { Ov0[r] += Cb[cidx + r]; Ov1[r] += Cb[cidx + 16 + r]; }
        psum += Cb[cidx + 32];

        const float inv = 1.0f / psum;
        __bf16* const obase = ob + (headQ + qt * 128 + qw * 32) * DH;
        #pragma unroll
        for (int r = 0; r < 16; ++r) {
            const int q_r = (r & 3) + 8 * (r >> 2) + 4 * hi;   // C-row [m74/m101]
            const float ivr = __shfl(inv, q_r);                // inv lives in lane q_r
            __bf16* op = obase + (size_t)q_r * DH + la31;
            op[0]  = (__bf16)(Ov0[r] * ivr);
            op[32] = (__bf16)(Ov1[r] * ivr);
        }
    }
}

// ---------------------------------------------------------------------------
extern "C" void kernel_launch(void* const* d_in, const int* in_sizes, int n_in,
                              void* d_out, int out_size, void* d_ws, size_t ws_size,
                              hipStream_t stream) {
    const float* x  = (const float*)d_in[0];
    const float* Wq = (const float*)d_in[1];
    const float* bq = (const float*)d_in[2];
    const float* Wk = (const float*)d_in[3];
    const float* bk = (const float*)d_in[4];
    const float* Wv = (const float*)d_in[5];
    const float* bv = (const float*)d_in[6];
    const float* Wc = (const float*)d_in[7];
    const float* bc = (const float*)d_in[8];
    float* out = (float*)d_out;

    // ws layout (48 MB):
    //   [ 0, 8MB): xb (bf16 4Mi) -- dead after QKV GEMM, reused as obf
    //   [ 8,14MB): wqkvb  [14,16MB): wcb
    //   [16,40MB): qkvb (q,k slabs [B,H,N,Dh]; q pre-scaled by SC2)
    //   [40,48MB): vT [B,H,Dh,N] (written directly by gemm_qkv256 V-part)
    char* base = (char*)d_ws;
    __bf16* xb    = (__bf16*)(base);
    __bf16* wqkvb = (__bf16*)(base + (size_t)8  * 1048576);
    __bf16* wcb   = (__bf16*)(base + (size_t)14 * 1048576);
    __bf16* qkvb  = (__bf16*)(base + (size_t)16 * 1048576);
    __bf16* vTb   = (__bf16*)(base + (size_t)40 * 1048576);
    __bf16* obf   = (__bf16*)(base);   // overwrites xb after attn

    __bf16* qhb = qkvb;
    __bf16* khb = qkvb + (size_t)M_ * D_;

    convert_k<<<dim3(4096), dim3(256), 0, stream>>>(
        x, Wq, Wk, Wv, Wc, xb, wqkvb, wcb);

    gemm_qkv256<<<dim3(192), dim3(512), 0, stream>>>(
        xb, wqkvb, bq, bk, bv, qkvb, vTb);

    attn_mfma<<<dim3(512), dim3(512), 0, stream>>>(qhb, khb, vTb, obf);

    gemm_out<<<dim3(8, 64, 1), dim3(256), 0, stream>>>(obf, wcb, bc, out);
}

// Round 8
// 184.732 us; speedup vs baseline: 1.0315x; 1.0315x over previous
//
#include <hip/hip_runtime.h>
#include <cstddef>
#include <cstdint>

#define B_  4
#define N_  1024
#define D_  1024
#define H_  16
#define DH  64
#define M_  4096   // B_*N_

#define SC2 0.04508422f   // (1/32) * log2(e)  — folded into Q at gemm epilogue

typedef __attribute__((ext_vector_type(4)))  float   f32x4;
typedef __attribute__((ext_vector_type(16))) float   f32x16;
typedef __attribute__((ext_vector_type(8)))  __bf16  bf16x8;
typedef __attribute__((ext_vector_type(4)))  unsigned int u32x4;

#define MFMA(a, b, c)   __builtin_amdgcn_mfma_f32_16x16x32_bf16((a), (b), (c), 0, 0, 0)
#define MFMA32(a, b, c) __builtin_amdgcn_mfma_f32_32x32x16_bf16((a), (b), (c), 0, 0, 0)
#define GLDS(gp, lp) __builtin_amdgcn_global_load_lds( \
    (__attribute__((address_space(1))) void*)(gp),     \
    (__attribute__((address_space(3))) void*)(lp), 16, 0, 0)

static __device__ __forceinline__ unsigned cvtpk(float lo, float hi) {
    unsigned r;
    asm("v_cvt_pk_bf16_f32 %0, %1, %2" : "=v"(r) : "v"(lo), "v"(hi));
    return r;
}

// ---------------------------------------------------------------------------
// convert: fp32 -> bf16 for x (4Mi) and Wq/Wk/Wv/Wc (4x1Mi). [verified R3]
// ---------------------------------------------------------------------------
__global__ __launch_bounds__(256) void convert_k(
    const float* __restrict__ x,  const float* __restrict__ Wq,
    const float* __restrict__ Wk, const float* __restrict__ Wv,
    const float* __restrict__ Wc,
    __bf16* __restrict__ xb, __bf16* __restrict__ wqkvb,
    __bf16* __restrict__ wcb)
{
    const unsigned u = blockIdx.x * 256u + threadIdx.x;
    const unsigned e = u * 8u;
    const float* src;
    __bf16* dst;
    if (e < 4194304u) { src = x + e; dst = xb + e; }
    else {
        const unsigned t2 = e - 4194304u;
        const unsigned wsel = t2 >> 20;
        const unsigned wo = t2 & 1048575u;
        src = (wsel == 0 ? Wq : wsel == 1 ? Wk : wsel == 2 ? Wv : Wc) + wo;
        dst = (wsel < 3 ? wqkvb + (size_t)wsel * 1048576u : wcb) + wo;
    }
    const float4 f0 = *(const float4*)(src);
    const float4 f1 = *(const float4*)(src + 4);
    bf16x8 r;
    r[0] = (__bf16)f0.x; r[1] = (__bf16)f0.y; r[2] = (__bf16)f0.z; r[3] = (__bf16)f0.w;
    r[4] = (__bf16)f1.x; r[5] = (__bf16)f1.y; r[6] = (__bf16)f1.z; r[7] = (__bf16)f1.w;
    *(bf16x8*)dst = r;
}

// ---------------------------------------------------------------------------
// QKV GEMM — R16 [verified: 58.5->42.4us, FETCH 37->24.8MB]: 8-phase 256^2
// template + XCD chunk swizzle + early staging. Byte-identical this round.
// ---------------------------------------------------------------------------
__global__ __launch_bounds__(512, 2) void gemm_qkv256(
    const __bf16* __restrict__ xb, const __bf16* __restrict__ Wb,
    const float* __restrict__ bq, const float* __restrict__ bk,
    const float* __restrict__ bv,
    __bf16* __restrict__ qk_out, __bf16* __restrict__ vT)
{
    __shared__ __bf16 ring[65536];   // [A: 4 x 8192][B: 4 x 8192] = 128KB

    const int tid  = threadIdx.x;
    const int w    = tid >> 6;        // 0..7
    const int lane = tid & 63;
    const int quad = lane >> 4;
    const int l15  = lane & 15;
    const int wr   = w >> 2;          // 0..1  (M half)
    const int wc   = w & 3;           // 0..3  (N quarter)

    const int bid = blockIdx.x;
    const bool VT = (bid >= 128);
    const int xcd = bid & 7;
    int m0, n0;
    const __bf16 *Ap, *Bp;
    if (!VT) {
        const int i  = bid >> 3;               // 0..15 within-XCD
        const int mt = (xcd >> 1) * 4 + (i >> 2);   // 0..15
        const int nt = (xcd & 1) * 4 + (i & 3);     // 0..7
        m0 = mt * 256; n0 = nt * 256;
        Ap = xb; Bp = Wb;
    } else {
        const int i  = (bid - 128) >> 3;       // 0..7
        m0 = (i & 3) * 256;                    // over e (Wv rows)
        n0 = (xcd * 2 + (i >> 2)) * 256;       // over m (xb rows)
        Ap = Wb + (size_t)2 * D_ * D_; Bp = xb;
    }

    const size_t sgl = (size_t)(w * 16 + l15) * D_ + quad * 8;
    const __bf16* Asrc = Ap + (size_t)m0 * D_ + sgl;
    const __bf16* Bsrc = Bp + (size_t)n0 * D_ + sgl;
    __bf16* const ringA = ring;
    __bf16* const ringB = ring + 32768;
    const int sdst = w * 1024;

#define STG_A(tt, h) do {                                               \
    const __bf16* s_ = Asrc + (size_t)(h) * 128 * D_ + (tt) * 64;       \
    __bf16* d_ = ringA + ((((tt) & 1) * 2 + (h)) * 8192) + sdst;        \
    GLDS(s_, d_); GLDS(s_ + 32, d_ + 512); } while (0)
#define STG_B(tt, h) do {                                               \
    const __bf16* s_ = Bsrc + (size_t)(h) * 128 * D_ + (tt) * 64;       \
    __bf16* d_ = ringB + ((((tt) & 1) * 2 + (h)) * 8192) + sdst;        \
    GLDS(s_, d_); GLDS(s_ + 32, d_ + 512); } while (0)

    f32x4 acc[8][4];
    #pragma unroll
    for (int i = 0; i < 8; ++i)
        #pragma unroll
        for (int j = 0; j < 4; ++j)
            acc[i][j] = (f32x4){0.f, 0.f, 0.f, 0.f};

    // prologue: order matters for the vmcnt ledger (oldest = B(0))
    STG_B(0, 0); STG_B(0, 1);
    STG_A(0, 0); STG_A(0, 1);
    STG_B(1, 0); STG_B(1, 1);

    const int rdo = lane * 8;

#define READ_A(q)                                                       \
    afr[0][0] = *(const bf16x8*)(Asl + ((2*(q)  )*2 + 0)*512);          \
    afr[0][1] = *(const bf16x8*)(Asl + ((2*(q)  )*2 + 1)*512);          \
    afr[1][0] = *(const bf16x8*)(Asl + ((2*(q)+1)*2 + 0)*512);          \
    afr[1][1] = *(const bf16x8*)(Asl + ((2*(q)+1)*2 + 1)*512);

#define PHASE_MFMA(q)                                                   \
    __builtin_amdgcn_s_barrier();                                       \
    asm volatile("s_waitcnt lgkmcnt(0)" ::: "memory");                  \
    __builtin_amdgcn_s_setprio(1);                                      \
    _Pragma("unroll")                                                   \
    for (int i = 0; i < 2; ++i)                                         \
      _Pragma("unroll")                                                 \
      for (int nt = 0; nt < 4; ++nt) {                                  \
        acc[2*(q)+i][nt] = MFMA(afr[i][0], bfr[nt][0], acc[2*(q)+i][nt]); \
        acc[2*(q)+i][nt] = MFMA(afr[i][1], bfr[nt][1], acc[2*(q)+i][nt]); \
      }                                                                 \
    __builtin_amdgcn_s_setprio(0);

    for (int t = 0; t < 16; ++t) {
        if (t < 15) asm volatile("s_waitcnt vmcnt(4)" ::: "memory");
        else        asm volatile("s_waitcnt vmcnt(0)" ::: "memory");
        __builtin_amdgcn_s_barrier();

        const __bf16* Asl = ringA + ((t & 1) * 2 + wr) * 8192 + rdo;
        const __bf16* Bsl = ringB + ((t & 1) * 2 + (wc >> 1)) * 8192
                                  + (wc & 1) * 4096 + rdo;
        bf16x8 afr[2][2], bfr[4][2];

        // ---- phase 0: stage both A(t+1) halves ----
        if (t < 15) { STG_A(t + 1, 0); STG_A(t + 1, 1); }
        #pragma unroll
        for (int nt = 0; nt < 4; ++nt) {
            bfr[nt][0] = *(const bf16x8*)(Bsl + (nt * 2 + 0) * 512);
            bfr[nt][1] = *(const bf16x8*)(Bsl + (nt * 2 + 1) * 512);
        }
        READ_A(0)
        PHASE_MFMA(0)
        __builtin_amdgcn_s_barrier();

        // ---- phase 1: stage B(t+2,0) ----
        if (t < 14) STG_B(t + 2, 0);
        READ_A(1)
        PHASE_MFMA(1)
        __builtin_amdgcn_s_barrier();

        // ---- phase 2: stage B(t+2,1) ----
        if (t < 14) STG_B(t + 2, 1);
        READ_A(2)
        PHASE_MFMA(2)
        __builtin_amdgcn_s_barrier();

        // ---- phase 3 ----
        READ_A(3)
        PHASE_MFMA(3)
    }
#undef STG_A
#undef STG_B
#undef READ_A
#undef PHASE_MFMA

    if (!VT) {
        const int zq = n0 >> 10;                  // 0:Q 1:K
        const float* bias = zq ? bk : bq;
        const float qs = zq ? 1.0f : SC2;         // fold softmax scale into Q
        const int nb = (n0 & 1023) + wc * 64;
        float bvv[4];
        #pragma unroll
        for (int nt = 0; nt < 4; ++nt) bvv[nt] = bias[nb + nt * 16 + l15];
        __bf16* C = qk_out + (size_t)zq * M_ * D_;
        #pragma unroll
        for (int mt = 0; mt < 8; ++mt) {
            #pragma unroll
            for (int r = 0; r < 4; ++r) {
                const int row = m0 + wr * 128 + mt * 16 + quad * 4 + r;
                #pragma unroll
                for (int nt = 0; nt < 4; ++nt) {
                    const int col = nb + nt * 16 + l15;
                    const size_t idx = (((size_t)(row >> 10) * H_ + (col >> 6)) * N_
                                        + (row & 1023)) * DH + (col & 63);
                    C[idx] = (__bf16)((acc[mt][nt][r] + bvv[nt]) * qs);
                }
            }
        }
    } else {
        #pragma unroll
        for (int mt = 0; mt < 8; ++mt) {
            #pragma unroll
            for (int r = 0; r < 4; ++r) {
                const int row = m0 + wr * 128 + mt * 16 + quad * 4 + r;   // e
                const float brow = bv[row];
                #pragma unroll
                for (int nt = 0; nt < 4; ++nt) {
                    const int col = n0 + wc * 64 + nt * 16 + l15;         // m
                    const size_t idx = (((size_t)(col >> 10) * H_ + (row >> 6)) * DH
                                        + (row & 63)) * N_ + (col & 1023);
                    vT[idx] = (__bf16)(acc[mt][nt][r] + brow);
                }
            }
        }
    }
}

// ---------------------------------------------------------------------------
// Final projection GEMM — R10's gemm64 MODE0 path [verified; R11 ring null].
// ---------------------------------------------------------------------------
__global__ __launch_bounds__(256, 6) void gemm_out(
    const __bf16* __restrict__ A0, const __bf16* __restrict__ Wb,
    const float* __restrict__ b0, float* __restrict__ Cb)
{
    __shared__ __bf16 As[2048];   // 64x32, frag-ordered (4KB)
    __shared__ __bf16 Bs[4096];   // 128x32, frag-ordered (8KB)

    const int tid  = threadIdx.x;
    const int w    = tid >> 6;
    const int lane = tid & 63;
    const int quad = lane >> 4;
    const int l15  = lane & 15;
    const int wr   = w >> 1, wc = w & 1;

    const int m0 = blockIdx.y * 64;
    const int n0 = blockIdx.x * 128;

    const int Tt = tid >> 6, ko = (tid >> 4) & 3, l = tid & 15;
    const size_t aoff  = (size_t)(m0 + Tt * 16 + l) * D_ + ko * 8;
    const size_t boff1 = (size_t)(n0 + Tt * 16 + l) * D_ + ko * 8;
    const size_t boff2 = boff1 + (size_t)64 * D_;
    __bf16* adst  = As + w * 512;
    __bf16* bdst1 = Bs + w * 512;
    __bf16* bdst2 = Bs + 2048 + w * 512;

    f32x4 acc[2][4];
    #pragma unroll
    for (int i = 0; i < 2; ++i)
        #pragma unroll
        for (int j = 0; j < 4; ++j)
            acc[i][j] = (f32x4){0.f, 0.f, 0.f, 0.f};

    for (int k0 = 0; k0 < D_; k0 += 32) {
        GLDS(A0 + aoff  + k0, adst);
        GLDS(Wb + boff1 + k0, bdst1);
        GLDS(Wb + boff2 + k0, bdst2);
        __syncthreads();

        bf16x8 af[2], bf[4];
        #pragma unroll
        for (int mt = 0; mt < 2; ++mt)
            af[mt] = *(const bf16x8*)(As + (((wr * 2 + mt) * 4 + quad) * 16 + l15) * 8);
        #pragma unroll
        for (int nt = 0; nt < 4; ++nt)
            bf[nt] = *(const bf16x8*)(Bs + (((wc * 4 + nt) * 4 + quad) * 16 + l15) * 8);
        #pragma unroll
        for (int mt = 0; mt < 2; ++mt)
            #pragma unroll
            for (int nt = 0; nt < 4; ++nt)
                acc[mt][nt] = MFMA(af[mt], bf[nt], acc[mt][nt]);
        __syncthreads();
    }

    float bvv[4];
    #pragma unroll
    for (int nt = 0; nt < 4; ++nt)
        bvv[nt] = b0[n0 + wc * 64 + nt * 16 + l15];
    #pragma unroll
    for (int mt = 0; mt < 2; ++mt) {
        #pragma unroll
        for (int r = 0; r < 4; ++r) {
            const int row = m0 + (wr * 2 + mt) * 16 + quad * 4 + r;
            #pragma unroll
            for (int nt = 0; nt < 4; ++nt) {
                const int col = n0 + wc * 64 + nt * 16 + l15;
                Cb[(size_t)row * D_ + col] = acc[mt][nt][r] + bvv[nt];
            }
        }
    }
}

// ---------------------------------------------------------------------------
// MFMA flash attention v10 — R18: revert R17's K-split (cross-round ledger:
// v9 cost ~+5us net; 8-tile loops + LDS combine ate the TLP gain), back to
// the R15-verified v8 structure (32x32 swapped-QK^T, in-register P, T12
// pack), PLUS a zero-cost LDS double-buffer: v8 used 16.5KB while the
// 512-block grid caps residency at 2 blocks/CU regardless (80KB budget) ->
// 32KB dbuf is free. Single barrier per K-tile: write kt->buf p; issue kt+1
// loads; lgkmcnt(0) (drains own writes AND own prev-tile ds_reads); s_barrier;
// compute(p). Ledger: writes to p^1 never collide with reads of p; kt+2's
// writes to p follow barrier kt+1, by which every wave's kt-reads of p are
// lgkm-drained. Raw s_barrier keeps vmcnt prefetch alive (R14 lesson).
// Barriers/tile 2 -> 1.
// ---------------------------------------------------------------------------
__global__ __launch_bounds__(256, 2) void attn_mfma(
    const __bf16* __restrict__ qh, const __bf16* __restrict__ kh,
    const __bf16* __restrict__ vT, __bf16* __restrict__ ob)
{
    __shared__ __align__(16) __bf16 Ks[2 * 4096];   // 2 x (8 frags x 512) = 16KB
    __shared__ __align__(16) __bf16 Vs[2 * 4096];

    const int tid  = threadIdx.x;
    const int w    = tid >> 6;        // 0..3
    const int lane = tid & 63;
    const int la31 = lane & 31;
    const int hi   = lane >> 5;       // 0/1

    const int bh = blockIdx.x >> 3;   // 0..63
    const int qt = blockIdx.x & 7;    // 128-q tile
    const int b  = bh >> 4;
    const int h  = bh & 15;

    const size_t headQ = (size_t)(b * H_ + h) * N_;

    // Q in registers: B-frag col=lane&31=q, k=d=(lane>>5)*8+j
    const int qrow = qt * 128 + w * 32 + la31;
    const __bf16* qp = qh + (headQ + qrow) * DH + hi * 8;
    const bf16x8 qf0 = *(const bf16x8*)(qp);
    const bf16x8 qf1 = *(const bf16x8*)(qp + 16);
    const bf16x8 qf2 = *(const bf16x8*)(qp + 32);
    const bf16x8 qf3 = *(const bf16x8*)(qp + 48);

    const __bf16* khead = kh + headQ * DH;                    // [N][64]
    const __bf16* vhead = vT + (size_t)(b * H_ + h) * DH * N_; // [64][N]

    // staging decode [verified R15]: frag-ordered, one bf16x8 store = 16B chunk
    const size_t koff0 = (size_t)la31 * DH + w * 16 + hi * 8;           // f=w (s=0)
    const size_t koff1 = koff0 + (size_t)32 * DH;                       // f=w+4 (s=1)
    const size_t voff0 = (size_t)((w & 1) * 32 + la31) * N_ + (w >> 1) * 16 + hi * 8;
    const size_t voff1 = voff0 + 32;                                    // g=w+4

    f32x16 Ov0, Ov1;
    #pragma unroll
    for (int r = 0; r < 16; ++r) { Ov0[r] = 0.f; Ov1[r] = 0.f; }
    float psum = 0.f;

    // prologue: tile 0 -> regs
    bf16x8 kr0 = *(const bf16x8*)(khead + koff0);
    bf16x8 kr1 = *(const bf16x8*)(khead + koff1);
    bf16x8 vr0 = *(const bf16x8*)(vhead + voff0);
    bf16x8 vr1 = *(const bf16x8*)(vhead + voff1);

#define PACK(earr, base, dst) do {                                        \
    unsigned U_ = cvtpk(earr[(base) + 0], earr[(base) + 1]);              \
    unsigned W_ = cvtpk(earr[(base) + 2], earr[(base) + 3]);              \
    unsigned V_ = cvtpk(earr[(base) + 4], earr[(base) + 5]);              \
    unsigned Z_ = cvtpk(earr[(base) + 6], earr[(base) + 7]);              \
    asm volatile("v_permlane32_swap_b32 %0, %1" : "+v"(U_), "+v"(V_));    \
    asm volatile("v_permlane32_swap_b32 %0, %1" : "+v"(W_), "+v"(Z_));    \
    u32x4 pw_ = {U_, W_, V_, Z_};                                         \
    dst = __builtin_bit_cast(bf16x8, pw_);                                \
} while (0)

    for (int kt = 0; kt < 16; ++kt) {
        const int p = kt & 1;
        __bf16* const kb = Ks + p * 4096;
        __bf16* const vb = Vs + p * 4096;

        // write tile kt into buf p (compiler inserts vmcnt wait on kr/vr)
        *(bf16x8*)(kb + tid * 8)        = kr0;
        *(bf16x8*)(kb + 2048 + tid * 8) = kr1;
        *(bf16x8*)(vb + tid * 8)        = vr0;
        *(bf16x8*)(vb + 2048 + tid * 8) = vr1;
        if (kt < 15) {                 // issue tile kt+1 loads; land during compute
            const __bf16* kp = khead + (size_t)(kt + 1) * 64 * DH;
            const __bf16* vp = vhead + (size_t)(kt + 1) * 64;
            kr0 = *(const bf16x8*)(kp + koff0);
            kr1 = *(const bf16x8*)(kp + koff1);
            vr0 = *(const bf16x8*)(vp + voff0);
            vr1 = *(const bf16x8*)(vp + voff1);
        }
        // publish: own writes drained (and own prev-tile ds_reads); barrier
        asm volatile("s_waitcnt lgkmcnt(0)" ::: "memory");
        __builtin_amdgcn_s_barrier();
        __builtin_amdgcn_sched_barrier(0);

        // ---- QK^T (swapped): sa = K . Q^T over d=64 ----
        f32x16 sa0, sa1;
        __builtin_amdgcn_s_setprio(1);
        {
            f32x16 z;
            #pragma unroll
            for (int r = 0; r < 16; ++r) z[r] = 0.f;
            bf16x8 kf;
            kf = *(const bf16x8*)(kb + 0 * 512 + lane * 8); sa0 = MFMA32(kf, qf0, z);
            kf = *(const bf16x8*)(kb + 1 * 512 + lane * 8); sa0 = MFMA32(kf, qf1, sa0);
            kf = *(const bf16x8*)(kb + 2 * 512 + lane * 8); sa0 = MFMA32(kf, qf2, sa0);
            kf = *(const bf16x8*)(kb + 3 * 512 + lane * 8); sa0 = MFMA32(kf, qf3, sa0);
            kf = *(const bf16x8*)(kb + 4 * 512 + lane * 8); sa1 = MFMA32(kf, qf0, z);
            kf = *(const bf16x8*)(kb + 5 * 512 + lane * 8); sa1 = MFMA32(kf, qf1, sa1);
            kf = *(const bf16x8*)(kb + 6 * 512 + lane * 8); sa1 = MFMA32(kf, qf2, sa1);
            kf = *(const bf16x8*)(kb + 7 * 512 + lane * 8); sa1 = MFMA32(kf, qf3, sa1);
        }
        __builtin_amdgcn_s_setprio(0);

        // ---- softmax (no max-sub, SC2 pre-folded): exp2 + in-reg psum ----
        float e0[16], e1[16];
        #pragma unroll
        for (int r = 0; r < 16; ++r) { e0[r] = __builtin_exp2f(sa0[r]); psum += e0[r]; }
        #pragma unroll
        for (int r = 0; r < 16; ++r) { e1[r] = __builtin_exp2f(sa1[r]); psum += e1[r]; }

        // ---- P -> A-frags: cvt_pk + permlane32_swap (T12) ----
        bf16x8 pf0, pf1, pf2, pf3;     // kb-blocks 0..3 (16-key contraction)
        PACK(e0, 0, pf0);
        PACK(e0, 8, pf1);
        PACK(e1, 0, pf2);
        PACK(e1, 8, pf3);

        // ---- PV: O += P . V ----
        __builtin_amdgcn_s_setprio(1);
        {
            bf16x8 vf;
            vf = *(const bf16x8*)(vb + 0 * 512 + lane * 8); Ov0 = MFMA32(pf0, vf, Ov0);
            vf = *(const bf16x8*)(vb + 2 * 512 + lane * 8); Ov0 = MFMA32(pf1, vf, Ov0);
            vf = *(const bf16x8*)(vb + 4 * 512 + lane * 8); Ov0 = MFMA32(pf2, vf, Ov0);
            vf = *(const bf16x8*)(vb + 6 * 512 + lane * 8); Ov0 = MFMA32(pf3, vf, Ov0);
            vf = *(const bf16x8*)(vb + 1 * 512 + lane * 8); Ov1 = MFMA32(pf0, vf, Ov1);
            vf = *(const bf16x8*)(vb + 3 * 512 + lane * 8); Ov1 = MFMA32(pf1, vf, Ov1);
            vf = *(const bf16x8*)(vb + 5 * 512 + lane * 8); Ov1 = MFMA32(pf2, vf, Ov1);
            vf = *(const bf16x8*)(vb + 7 * 512 + lane * 8); Ov1 = MFMA32(pf3, vf, Ov1);
        }
        __builtin_amdgcn_s_setprio(0);
    }
#undef PACK

    // lane pair (l, l^32) holds the two key-halves of query q=lane&31
    psum += __shfl_xor(psum, 32);
    const float inv = 1.0f / psum;

    __bf16* const obase = ob + (headQ + qt * 128 + w * 32) * DH;
    #pragma unroll
    for (int r = 0; r < 16; ++r) {
        const int q_r = (r & 3) + 8 * (r >> 2) + 4 * hi;   // C-row [m74/m101]
        const float ivr = __shfl(inv, q_r);                // inv lives in lane q_r
        __bf16* op = obase + (size_t)q_r * DH + la31;
        op[0]  = (__bf16)(Ov0[r] * ivr);
        op[32] = (__bf16)(Ov1[r] * ivr);
    }
}

// ---------------------------------------------------------------------------
extern "C" void kernel_launch(void* const* d_in, const int* in_sizes, int n_in,
                              void* d_out, int out_size, void* d_ws, size_t ws_size,
                              hipStream_t stream) {
    const float* x  = (const float*)d_in[0];
    const float* Wq = (const float*)d_in[1];
    const float* bq = (const float*)d_in[2];
    const float* Wk = (const float*)d_in[3];
    const float* bk = (const float*)d_in[4];
    const float* Wv = (const float*)d_in[5];
    const float* bv = (const float*)d_in[6];
    const float* Wc = (const float*)d_in[7];
    const float* bc = (const float*)d_in[8];
    float* out = (float*)d_out;

    // ws layout (48 MB):
    //   [ 0, 8MB): xb (bf16 4Mi) -- dead after QKV GEMM, reused as obf
    //   [ 8,14MB): wqkvb  [14,16MB): wcb
    //   [16,40MB): qkvb (q,k slabs [B,H,N,Dh]; q pre-scaled by SC2)
    //   [40,48MB): vT [B,H,Dh,N] (written directly by gemm_qkv256 V-part)
    char* base = (char*)d_ws;
    __bf16* xb    = (__bf16*)(base);
    __bf16* wqkvb = (__bf16*)(base + (size_t)8  * 1048576);
    __bf16* wcb   = (__bf16*)(base + (size_t)14 * 1048576);
    __bf16* qkvb  = (__bf16*)(base + (size_t)16 * 1048576);
    __bf16* vTb   = (__bf16*)(base + (size_t)40 * 1048576);
    __bf16* obf   = (__bf16*)(base);   // overwrites xb after attn

    __bf16* qhb = qkvb;
    __bf16* khb = qkvb + (size_t)M_ * D_;

    convert_k<<<dim3(4096), dim3(256), 0, stream>>>(
        x, Wq, Wk, Wv, Wc, xb, wqkvb, wcb);

    gemm_qkv256<<<dim3(192), dim3(512), 0, stream>>>(
        xb, wqkvb, bq, bk, bv, qkvb, vTb);

    attn_mfma<<<dim3(512), dim3(256), 0, stream>>>(qhb, khb, vTb, obf);

    gemm_out<<<dim3(8, 64, 1), dim3(256), 0, stream>>>(obf, wcb, bc, out);
}